// Round 6
// baseline (275.389 us; speedup 1.0000x reference)
//
#include <hip/hip_runtime.h>
#include <math.h>

// Problem constants
#define B_   8
#define T_   2048
#define V_   1024
#define C_   128
#define NB2  64     // 2*NB
#define L_   32     // chunk length for the linearized recurrence
#define NC_  64     // T_/L_

typedef _Float16 f16_t;
typedef f16_t f16x8 __attribute__((ext_vector_type(8)));
typedef float f32x4 __attribute__((ext_vector_type(4)));

__device__ __forceinline__ float sigmoidf_(float x){ return 1.0f/(1.0f+expf(-x)); }

// direct global->LDS DMA, 16 B per lane (dest must be linear: base + lane*16)
__device__ __forceinline__ void gload_lds16(const void* g, void* l){
  __builtin_amdgcn_global_load_lds(
      (const __attribute__((address_space(1))) uint32_t*)g,
      (__attribute__((address_space(3))) uint32_t*)l, 16, 0, 0);
}

// ---------------------------------------------------------------------------
// K0: weights. proj 0..2: softmax(basis@coeffs^T, axis=V) -> fp16,
//     TRANSPOSED (Wt[c][v]) for MFMA B-fragment reads.
//     proj 3: Wo (V,C) row-major fp16 (rows are B-fragments for out GEMM).
// ---------------------------------------------------------------------------
__global__ __launch_bounds__(256) void weights_kernel(
    const float* __restrict__ basis,
    const float* __restrict__ qc, const float* __restrict__ kc,
    const float* __restrict__ vc, const float* __restrict__ oc,
    f16_t* __restrict__ Wo, f16_t* __restrict__ Wt)
{
  int blk  = blockIdx.x;
  int proj = blk >> 7;
  int c    = blk & 127;
  const float* coeffs = (proj==0)?qc : (proj==1)?kc : (proj==2)?vc : oc;

  __shared__ float coef[NB2];
  __shared__ float red[256];
  int tid = threadIdx.x;
  if (tid < NB2) coef[tid] = coeffs[c*NB2 + tid];
  __syncthreads();

  float l[4];
  for (int i=0;i<4;i++){
    int v = tid + i*256;
    const float4* bp = (const float4*)(basis + (size_t)v*NB2);
    float s = 0.f;
    #pragma unroll
    for (int f=0; f<NB2/4; f++){
      float4 b4 = bp[f];
      s += b4.x*coef[f*4+0] + b4.y*coef[f*4+1] + b4.z*coef[f*4+2] + b4.w*coef[f*4+3];
    }
    l[i] = s;
  }
  if (proj == 3){
    for (int i=0;i<4;i++){ int v = tid+i*256; Wo[(size_t)v*C_ + c] = (f16_t)l[i]; }
    return;
  }
  float mx = fmaxf(fmaxf(l[0],l[1]), fmaxf(l[2],l[3]));
  red[tid] = mx; __syncthreads();
  for (int s=128; s>0; s>>=1){ if (tid<s) red[tid] = fmaxf(red[tid], red[tid+s]); __syncthreads(); }
  mx = red[0]; __syncthreads();
  float sum = 0.f;
  for (int i=0;i<4;i++) sum += expf(l[i]-mx);
  red[tid] = sum; __syncthreads();
  for (int s=128; s>0; s>>=1){ if (tid<s) red[tid] += red[tid+s]; __syncthreads(); }
  float inv = 1.0f/red[0];
  f16_t* tp = Wt + ((size_t)proj*C_ + c)*V_;
  for (int i=0;i<4;i++){
    int v = tid+i*256;
    tp[v] = (f16_t)(expf(l[i]-mx)*inv);
  }
}

// ---------------------------------------------------------------------------
// K1 (FUSED): q,k,v = x @ [Wq|Wk|Wv] in ONE pass over x.
// 512 thr = 8 waves (2x4), wave tile 32x96, BM=64, N=384, BK=64, 16 K-iters.
// B staged via global_load_lds (linear LDS, XOR-swizzled source + same XOR on
// ds_read). LDS 57.6 KB, grid 256 = 1 block/CU.
// ---------------------------------------------------------------------------
#define BM 64
#define BN 128
#define BK 64
#define PADK 72   // LDS row stride in f16 for A (144 B, breaks pow2 banks)
#define NF_  384  // 3*C
#define NT_PROJ (V_/BK)   // 16

__global__ __launch_bounds__(512, 1) void proj_fused_kernel(
    const float* __restrict__ x,
    const f16_t* __restrict__ Wt,   // [384][1024] f16 (= [3][C][V])
    float* __restrict__ out)        // [3][M][C]
{
  const int M = B_*T_;
  int m0 = blockIdx.x * BM;

  __shared__ __align__(16) f16_t As[BM][PADK];   // 9.2 KB
  __shared__ __align__(16) f16_t Bsh[NF_*BK];    // 48 KB, swizzled chunks

  int tid  = threadIdx.x;          // 0..511
  int lane = tid & 63;
  int w    = tid >> 6;             // 0..7
  int wm   = (w >> 2) * 32;        // 0,32
  int wn   = (w & 3) * 96;         // 0,96,192,288
  int lr   = lane & 15;
  int lg   = lane >> 4;

  const float* xbase = x + (size_t)m0*V_;

  f32x4 acc[2][6] = {};

  for (int kt = 0; kt < NT_PROJ; kt++){
    #pragma unroll
    for (int i=0;i<6;i++){
      int ci = i*512 + tid;
      int r  = ci >> 3, ch = ci & 7;
      const f16_t* src = Wt + (size_t)r*V_ + kt*BK + ((ch ^ (r&7))<<3);
      gload_lds16(src, &Bsh[ci*8]);
    }
    #pragma unroll
    for (int i=0;i<2;i++){
      int ci = i*512 + tid;
      int row = ci >> 4, q = ci & 15;
      float4 xv = *(const float4*)(xbase + (size_t)row*V_ + kt*BK + q*4);
      union { f16_t h[4]; ushort4 u; } hh;
      hh.h[0]=(f16_t)xv.x; hh.h[1]=(f16_t)xv.y; hh.h[2]=(f16_t)xv.z; hh.h[3]=(f16_t)xv.w;
      *(ushort4*)&As[row][q*4] = hh.u;
    }
    __syncthreads();

    #pragma unroll
    for (int kh=0; kh<2; kh++){
      f16x8 a[2];
      #pragma unroll
      for (int mt=0; mt<2; mt++)
        a[mt] = *(f16x8*)&As[wm + mt*16 + lr][kh*32 + lg*8];
      #pragma unroll
      for (int nt=0; nt<6; nt++){
        int n  = wn + nt*16 + lr;
        int c0 = kh*4 + lg;
        f16x8 b = *(f16x8*)&Bsh[n*BK + ((c0 ^ (n&7))<<3)];
        #pragma unroll
        for (int mt=0; mt<2; mt++)
          acc[mt][nt] = __builtin_amdgcn_mfma_f32_16x16x32_f16(a[mt], b, acc[mt][nt], 0,0,0);
      }
    }
    __syncthreads();
  }

  #pragma unroll
  for (int mt=0; mt<2; mt++)
    #pragma unroll
    for (int nt=0; nt<6; nt++){
      int n   = wn + nt*16 + lr;
      int p   = n >> 7;
      int col = n & 127;
      float* op = out + (size_t)p*M*C_;
      #pragma unroll
      for (int r=0; r<4; r++){
        int row = m0 + wm + mt*16 + lg*4 + r;
        op[(size_t)row*C_ + col] = acc[mt][nt][r];
      }
    }
}

// ---------------------------------------------------------------------------
// K2: per-chunk KV summary: kv[b][ci][c][dd] = sum_j d^{L-1-j} k_j[c] v_j[dd]
// ---------------------------------------------------------------------------
__global__ __launch_bounds__(256) void kvsum_kernel(
    const float* __restrict__ k, const float* __restrict__ v,
    const float* __restrict__ dptr, float* __restrict__ kv)
{
  int ci = blockIdx.x, b = blockIdx.y;
  float d = sigmoidf_(dptr[0]);
  __shared__ float ks[L_][132];
  __shared__ float vs[L_][132];
  int tid = threadIdx.x;
  const float* kp = k + ((size_t)b*T_ + ci*L_)*C_;
  const float* vp = v + ((size_t)b*T_ + ci*L_)*C_;
  #pragma unroll
  for (int i=0;i<4;i++){
    int idx = tid + i*256;
    int j = idx >> 5, c4 = idx & 31;
    float w = powf(d, (float)(L_-1-j));
    float4 k4 = *(const float4*)(kp + (size_t)j*C_ + c4*4);
    k4.x*=w; k4.y*=w; k4.z*=w; k4.w*=w;
    *(float4*)&ks[j][c4*4] = k4;
    *(float4*)&vs[j][c4*4] = *(const float4*)(vp + (size_t)j*C_ + c4*4);
  }
  __syncthreads();
  int tc = tid >> 4, td = tid & 15;
  float acc[8][8] = {};
  for (int j=0;j<L_;j++){
    float kr[8], vr[8];
    *(float4*)&kr[0] = *(float4*)&ks[j][tc*8];
    *(float4*)&kr[4] = *(float4*)&ks[j][tc*8+4];
    *(float4*)&vr[0] = *(float4*)&vs[j][td*8];
    *(float4*)&vr[4] = *(float4*)&vs[j][td*8+4];
    #pragma unroll
    for (int a=0;a<8;a++)
      #pragma unroll
      for (int bb=0;bb<8;bb++) acc[a][bb] += kr[a]*vr[bb];
  }
  float* op = kv + ((size_t)b*NC_ + ci)*C_*C_;
  for (int a=0;a<8;a++)
    for (int b4=0;b4<2;b4++)
      *(float4*)(op + (size_t)(tc*8+a)*C_ + td*8 + b4*4) =
        make_float4(acc[a][b4*4],acc[a][b4*4+1],acc[a][b4*4+2],acc[a][b4*4+3]);
}

// ---------------------------------------------------------------------------
// K3: in-place exclusive scan over chunks
// ---------------------------------------------------------------------------
__global__ __launch_bounds__(256) void scan_kernel(
    float* __restrict__ kv, const float* __restrict__ dptr)
{
  int idx = blockIdx.x*256 + threadIdx.x;
  int b = idx >> 14, e = idx & 16383;
  float d  = sigmoidf_(dptr[0]);
  float dL = powf(d, (float)L_);
  float* p = kv + (size_t)b*NC_*C_*C_ + e;
  float m = 0.f;
  for (int i=0;i<NC_;i++){
    float s = p[(size_t)i*C_*C_];
    p[(size_t)i*C_*C_] = m;
    m = dL*m + s;
  }
}

// ---------------------------------------------------------------------------
// K4 v4: COLUMN-SPLIT intra. grid (NC_, B_, 2); each block computes 32 rows x
// 64 output cols. M chunks are 32x64 (8 KB) DMA'd via global_load_lds.
// LDS ~53 KB -> 3 blocks/CU (12 waves/CU, was 8). Scores (q.k, full 128-dim)
// computed redundantly in both halves (~1/5 of block time).
// Stride 130 on qs/kvs (520 B, odd mod-32-banks) to fit 3 blocks/CU.
// ---------------------------------------------------------------------------
__global__ __launch_bounds__(256) void intra_kernel(
    const float* __restrict__ q, const float* __restrict__ k,
    const float* __restrict__ v, const float* __restrict__ Minit,
    const float* __restrict__ dptr,
    f16_t* __restrict__ ret)
{
  int ci = blockIdx.x, b = blockIdx.y, h = blockIdx.z;
  int tid = threadIdx.x;
  float d = sigmoidf_(dptr[0]);
  __shared__ float qs[L_][130];                  // 16.6 KB (full q rows)
  __shared__ float kvs[L_][130];                 // k full, then v half
  __shared__ __align__(16) float Ms[2][L_][64];  // 16 KB (DMA dest, linear)
  __shared__ float ps[L_][33];
  __shared__ float dpow[L_+1];
  if (tid <= L_) dpow[tid] = powf(d, (float)tid);

  const float* qp = q + ((size_t)b*T_ + ci*L_)*C_;
  const float* kp = k + ((size_t)b*T_ + ci*L_)*C_;
  const float* vp = v + ((size_t)b*T_ + ci*L_)*C_;
  const float* Mp = Minit + ((size_t)b*NC_ + ci)*C_*C_ + h*64;  // col offset

  // ---- DMA chunk 0 -> Ms[0]: 32 rows x 64 cols = 512 x 16B, 2 per thread
  #pragma unroll
  for (int i=0;i<2;i++){
    int cidx = i*256 + tid;
    int r = cidx >> 4, c4 = cidx & 15;
    gload_lds16(Mp + (size_t)r*C_ + c4*4, &Ms[0][0][0] + cidx*4);
  }
  // ---- stage q, k (full rows): 32 rows x 32 float4 = 1024, 4 per thread
  #pragma unroll
  for (int i=0;i<4;i++){
    int idx = tid + i*256;
    int j = idx >> 5, c4 = idx & 31;
    *(float4*)&qs[j][c4*4]  = *(const float4*)(qp + (size_t)j*C_ + c4*4);
    *(float4*)&kvs[j][c4*4] = *(const float4*)(kp + (size_t)j*C_ + c4*4);
  }
  __syncthreads();   // B0: chunk0 + qs + kvs(k) visible

  // ---- DMA chunk 1 -> Ms[1] (drains at B1, hidden under scores)
  #pragma unroll
  for (int i=0;i<2;i++){
    int cidx = i*256 + tid;
    int r = cidx >> 4, c4 = cidx & 15;
    gload_lds16(Mp + (size_t)(L_ + r)*C_ + c4*4, &Ms[1][0][0] + cidx*4);
  }

  // ---- scores ps (full 128-dim dots)
  {
    int tr = tid >> 4, tj = tid & 15;
    float s[2][2] = {};
    for (int c4=0;c4<32;c4++){
      float4 q4[2], k4[2];
      #pragma unroll
      for (int i=0;i<2;i++) q4[i] = *(float4*)&qs[tr*2+i][c4*4];
      #pragma unroll
      for (int i=0;i<2;i++) k4[i] = *(float4*)&kvs[tj*2+i][c4*4];
      #pragma unroll
      for (int a=0;a<2;a++)
        #pragma unroll
        for (int bb=0;bb<2;bb++)
          s[a][bb] += q4[a].x*k4[bb].x + q4[a].y*k4[bb].y + q4[a].z*k4[bb].z + q4[a].w*k4[bb].w;
    }
    #pragma unroll
    for (int a=0;a<2;a++)
      #pragma unroll
      for (int bb=0;bb<2;bb++){
        int r = tr*2+a, j = tj*2+bb;
        ps[r][j] = (j < r) ? s[a][bb]*dpow[r-1-j] : 0.f;
      }
  }
  __syncthreads();   // B1: ps + chunk1 visible; kvs(k) dead

  // ---- stage v half into kvs (read only after B2): 512 float4, 2/thread
  #pragma unroll
  for (int i=0;i<2;i++){
    int idx = tid + i*256;
    int j = idx >> 4, c4 = idx & 15;
    *(float4*)&kvs[j][c4*4] = *(const float4*)(vp + (size_t)j*C_ + h*64 + c4*4);
  }

  int tx = tid & 15, ty = tid >> 4;   // tx: 16 col-groups, ty: 16 row-pairs
  float acc[2][4] = {};

#define INTRA_MCHUNK(buf, cc) do { \
    for (int c=0;c<L_;c++){ \
      float4 m4 = *(float4*)&Ms[buf][c][tx*4]; \
      _Pragma("unroll") \
      for (int r=0;r<2;r++){ \
        float qv = qs[ty*2+r][(cc)*L_ + c]; \
        acc[r][0] += qv*m4.x; acc[r][1] += qv*m4.y; \
        acc[r][2] += qv*m4.z; acc[r][3] += qv*m4.w; \
      } \
    } \
  } while(0)

  INTRA_MCHUNK(0, 0);
  __syncthreads();   // B2: Ms[0] reads done; kvs(v) visible

  // ---- DMA chunk 2 -> Ms[0] (drains at B3, hidden under MCHUNK(1,1))
  #pragma unroll
  for (int i=0;i<2;i++){
    int cidx = i*256 + tid;
    int r = cidx >> 4, c4 = cidx & 15;
    gload_lds16(Mp + (size_t)(2*L_ + r)*C_ + c4*4, &Ms[0][0][0] + cidx*4);
  }
  INTRA_MCHUNK(1, 1);
  __syncthreads();   // B3: chunk2 visible; Ms[1] reads done

  // ---- DMA chunk 3 -> Ms[1] (drains at B4, hidden under MCHUNK(0,2))
  #pragma unroll
  for (int i=0;i<2;i++){
    int cidx = i*256 + tid;
    int r = cidx >> 4, c4 = cidx & 15;
    gload_lds16(Mp + (size_t)(3*L_ + r)*C_ + c4*4, &Ms[1][0][0] + cidx*4);
  }
  INTRA_MCHUNK(0, 2);
  __syncthreads();   // B4: chunk3 visible

  INTRA_MCHUNK(1, 3);
#undef INTRA_MCHUNK

  #pragma unroll
  for (int r=0;r<2;r++){
    float sc = dpow[ty*2+r];
    #pragma unroll
    for (int j=0;j<4;j++) acc[r][j] *= sc;
  }
  for (int j=0;j<L_;j++){
    float4 v4 = *(float4*)&kvs[j][tx*4];
    #pragma unroll
    for (int r=0;r<2;r++){
      float p = ps[ty*2+r][j];
      acc[r][0] += p*v4.x; acc[r][1] += p*v4.y; acc[r][2] += p*v4.z; acc[r][3] += p*v4.w;
    }
  }
  size_t rbase = ((size_t)b*T_ + ci*L_)*C_ + h*64;
  for (int r=0;r<2;r++){
    union { f16_t h4[4]; ushort4 u; } hh;
    #pragma unroll
    for (int j=0;j<4;j++) hh.h4[j] = (f16_t)acc[r][j];
    *(ushort4*)(ret + rbase + (size_t)(ty*2+r)*C_ + tx*4) = hh.u;
  }
}

// ---------------------------------------------------------------------------
// K5 v2: out = (ret @ Wo^T) * out_scale -- BARRIER-FREE direct-fragment MFMA.
// K=128 is short and Wo (256 KB f16) is L2-resident: load MFMA fragments
// straight from global (16 B/lane), no LDS, no __syncthreads. Zero LDS ->
// ~8 blocks/CU all-resident; kernel streams against the 64 MB output write.
// grid (256, 8), 256 thr = 4 waves (2x2 of 32x64 wave tiles).
// ---------------------------------------------------------------------------
__global__ __launch_bounds__(256) void out_mfma_kernel(
    const f16_t* __restrict__ A, const f16_t* __restrict__ Bw,
    const float* __restrict__ scl, float* __restrict__ out)
{
  int m0 = blockIdx.x * BM;
  int n0 = blockIdx.y * BN;
  float osc = scl[0];

  int tid  = threadIdx.x;
  int lane = tid & 63;
  int w    = tid >> 6;
  int wm   = (w >> 1) * 32;
  int wn   = (w & 1) * 64;
  int lr   = lane & 15;
  int lg   = lane >> 4;

  f32x4 acc[2][4] = {};

  #pragma unroll
  for (int kh=0; kh<4; kh++){
    f16x8 a[2];
    #pragma unroll
    for (int mt=0; mt<2; mt++)
      a[mt] = *(const f16x8*)(A + (size_t)(m0 + wm + mt*16 + lr)*C_ + kh*32 + lg*8);
    #pragma unroll
    for (int nt=0; nt<4; nt++){
      f16x8 bfr = *(const f16x8*)(Bw + (size_t)(n0 + wn + nt*16 + lr)*C_ + kh*32 + lg*8);
      #pragma unroll
      for (int mt=0; mt<2; mt++)
        acc[mt][nt] = __builtin_amdgcn_mfma_f32_16x16x32_f16(a[mt], bfr, acc[mt][nt], 0,0,0);
    }
  }

  #pragma unroll
  for (int mt=0; mt<2; mt++)
    #pragma unroll
    for (int nt=0; nt<4; nt++)
      #pragma unroll
      for (int r=0; r<4; r++){
        int row = m0 + wm + mt*16 + lg*4 + r;
        int col = n0 + wn + nt*16 + lr;
        out[(size_t)row*V_ + col] = acc[mt][nt][r] * osc;
      }
}

// ---------------------------------------------------------------------------
extern "C" void kernel_launch(void* const* d_in, const int* in_sizes, int n_in,
                              void* d_out, int out_size, void* d_ws, size_t ws_size,
                              hipStream_t stream)
{
  const float* x     = (const float*)d_in[0];
  const float* basis = (const float*)d_in[1];
  const float* qc    = (const float*)d_in[2];
  const float* kc    = (const float*)d_in[3];
  const float* vc    = (const float*)d_in[4];
  const float* oc    = (const float*)d_in[5];
  const float* dptr  = (const float*)d_in[6];
  const float* sptr  = (const float*)d_in[7];
  float* out = (float*)d_out;
  float* ws  = (float*)d_ws;

  const size_t M = (size_t)B_*T_;
  // Workspace layout (offsets in FLOAT units):
  //   Wo   f16 V*C      @ 0        (65536 f)
  //   Wt   f16 3*C*V    @ 65536    (196608 f)
  //   qkv  f32 3*M*C    @ 262144
  //   ret  f16 M*C      @ 6553600
  //   kv   f32 B*NC*C*C @ 7602176
  f16_t* Wo  = (f16_t*)ws;
  f16_t* Wt  = (f16_t*)(ws + 65536);
  float* qkv = ws + 262144;
  f16_t* ret = (f16_t*)(ws + 6553600);
  float* kv  = ws + 7602176;

  float* q = qkv;
  float* k = qkv + M*C_;
  float* v = qkv + 2*M*C_;

  hipLaunchKernelGGL(weights_kernel, dim3(512), dim3(256), 0, stream,
                     basis, qc, kc, vc, oc, Wo, Wt);
  hipLaunchKernelGGL(proj_fused_kernel, dim3(256), dim3(512), 0, stream,
                     x, Wt, qkv);
  hipLaunchKernelGGL(kvsum_kernel, dim3(NC_, B_), dim3(256), 0, stream, k, v, dptr, kv);
  hipLaunchKernelGGL(scan_kernel, dim3(512), dim3(256), 0, stream, kv, dptr);
  hipLaunchKernelGGL(intra_kernel, dim3(NC_, B_, 2), dim3(256), 0, stream,
                     q, k, v, kv, dptr, ret);
  hipLaunchKernelGGL(out_mfma_kernel, dim3(256, 8), dim3(256), 0, stream,
                     ret, Wo, sptr, out);
}

// Round 7
// 250.174 us; speedup vs baseline: 1.1008x; 1.1008x over previous
//
#include <hip/hip_runtime.h>
#include <math.h>

// Problem constants
#define B_   8
#define T_   2048
#define V_   1024
#define C_   128
#define NB2  64     // 2*NB
#define L_   32     // chunk length for the linearized recurrence
#define NC_  64     // T_/L_

typedef _Float16 f16_t;
typedef f16_t f16x8 __attribute__((ext_vector_type(8)));
typedef float f32x4 __attribute__((ext_vector_type(4)));

__device__ __forceinline__ float sigmoidf_(float x){ return 1.0f/(1.0f+expf(-x)); }

// direct global->LDS DMA, 16 B per lane (dest must be linear: base + lane*16)
__device__ __forceinline__ void gload_lds16(const void* g, void* l){
  __builtin_amdgcn_global_load_lds(
      (const __attribute__((address_space(1))) uint32_t*)g,
      (__attribute__((address_space(3))) uint32_t*)l, 16, 0, 0);
}

// ---------------------------------------------------------------------------
// K0: weights. proj 0..2: softmax(basis@coeffs^T, axis=V) -> fp16,
//     TRANSPOSED (Wt[c][v]) for MFMA B-fragment reads.
//     proj 3: Wo (V,C) row-major fp16 (rows are B-fragments for out GEMM).
// ---------------------------------------------------------------------------
__global__ __launch_bounds__(256) void weights_kernel(
    const float* __restrict__ basis,
    const float* __restrict__ qc, const float* __restrict__ kc,
    const float* __restrict__ vc, const float* __restrict__ oc,
    f16_t* __restrict__ Wo, f16_t* __restrict__ Wt)
{
  int blk  = blockIdx.x;
  int proj = blk >> 7;
  int c    = blk & 127;
  const float* coeffs = (proj==0)?qc : (proj==1)?kc : (proj==2)?vc : oc;

  __shared__ float coef[NB2];
  __shared__ float red[256];
  int tid = threadIdx.x;
  if (tid < NB2) coef[tid] = coeffs[c*NB2 + tid];
  __syncthreads();

  float l[4];
  for (int i=0;i<4;i++){
    int v = tid + i*256;
    const float4* bp = (const float4*)(basis + (size_t)v*NB2);
    float s = 0.f;
    #pragma unroll
    for (int f=0; f<NB2/4; f++){
      float4 b4 = bp[f];
      s += b4.x*coef[f*4+0] + b4.y*coef[f*4+1] + b4.z*coef[f*4+2] + b4.w*coef[f*4+3];
    }
    l[i] = s;
  }
  if (proj == 3){
    for (int i=0;i<4;i++){ int v = tid+i*256; Wo[(size_t)v*C_ + c] = (f16_t)l[i]; }
    return;
  }
  float mx = fmaxf(fmaxf(l[0],l[1]), fmaxf(l[2],l[3]));
  red[tid] = mx; __syncthreads();
  for (int s=128; s>0; s>>=1){ if (tid<s) red[tid] = fmaxf(red[tid], red[tid+s]); __syncthreads(); }
  mx = red[0]; __syncthreads();
  float sum = 0.f;
  for (int i=0;i<4;i++) sum += expf(l[i]-mx);
  red[tid] = sum; __syncthreads();
  for (int s=128; s>0; s>>=1){ if (tid<s) red[tid] += red[tid+s]; __syncthreads(); }
  float inv = 1.0f/red[0];
  f16_t* tp = Wt + ((size_t)proj*C_ + c)*V_;
  for (int i=0;i<4;i++){
    int v = tid+i*256;
    tp[v] = (f16_t)(expf(l[i]-mx)*inv);
  }
}

// ---------------------------------------------------------------------------
// K1 (FUSED): q,k,v = x @ [Wq|Wk|Wv] in ONE pass over x.
// 512 thr = 8 waves (2x4), wave tile 32x96, BM=64, N=384, BK=64, 16 K-iters.
// B staged via global_load_lds (linear LDS, XOR-swizzled source + same XOR on
// ds_read). LDS 57.6 KB, grid 256 = 1 block/CU.
// ---------------------------------------------------------------------------
#define BM 64
#define BN 128
#define BK 64
#define PADK 72   // LDS row stride in f16 for A (144 B, breaks pow2 banks)
#define NF_  384  // 3*C
#define NT_PROJ (V_/BK)   // 16

__global__ __launch_bounds__(512, 1) void proj_fused_kernel(
    const float* __restrict__ x,
    const f16_t* __restrict__ Wt,   // [384][1024] f16 (= [3][C][V])
    float* __restrict__ out)        // [3][M][C]
{
  const int M = B_*T_;
  int m0 = blockIdx.x * BM;

  __shared__ __align__(16) f16_t As[BM][PADK];   // 9.2 KB
  __shared__ __align__(16) f16_t Bsh[NF_*BK];    // 48 KB, swizzled chunks

  int tid  = threadIdx.x;          // 0..511
  int lane = tid & 63;
  int w    = tid >> 6;             // 0..7
  int wm   = (w >> 2) * 32;        // 0,32
  int wn   = (w & 3) * 96;         // 0,96,192,288
  int lr   = lane & 15;
  int lg   = lane >> 4;

  const float* xbase = x + (size_t)m0*V_;

  f32x4 acc[2][6] = {};

  for (int kt = 0; kt < NT_PROJ; kt++){
    #pragma unroll
    for (int i=0;i<6;i++){
      int ci = i*512 + tid;
      int r  = ci >> 3, ch = ci & 7;
      const f16_t* src = Wt + (size_t)r*V_ + kt*BK + ((ch ^ (r&7))<<3);
      gload_lds16(src, &Bsh[ci*8]);
    }
    #pragma unroll
    for (int i=0;i<2;i++){
      int ci = i*512 + tid;
      int row = ci >> 4, q = ci & 15;
      float4 xv = *(const float4*)(xbase + (size_t)row*V_ + kt*BK + q*4);
      union { f16_t h[4]; ushort4 u; } hh;
      hh.h[0]=(f16_t)xv.x; hh.h[1]=(f16_t)xv.y; hh.h[2]=(f16_t)xv.z; hh.h[3]=(f16_t)xv.w;
      *(ushort4*)&As[row][q*4] = hh.u;
    }
    __syncthreads();

    #pragma unroll
    for (int kh=0; kh<2; kh++){
      f16x8 a[2];
      #pragma unroll
      for (int mt=0; mt<2; mt++)
        a[mt] = *(f16x8*)&As[wm + mt*16 + lr][kh*32 + lg*8];
      #pragma unroll
      for (int nt=0; nt<6; nt++){
        int n  = wn + nt*16 + lr;
        int c0 = kh*4 + lg;
        f16x8 b = *(f16x8*)&Bsh[n*BK + ((c0 ^ (n&7))<<3)];
        #pragma unroll
        for (int mt=0; mt<2; mt++)
          acc[mt][nt] = __builtin_amdgcn_mfma_f32_16x16x32_f16(a[mt], b, acc[mt][nt], 0,0,0);
      }
    }
    __syncthreads();
  }

  #pragma unroll
  for (int mt=0; mt<2; mt++)
    #pragma unroll
    for (int nt=0; nt<6; nt++){
      int n   = wn + nt*16 + lr;
      int p   = n >> 7;
      int col = n & 127;
      float* op = out + (size_t)p*M*C_;
      #pragma unroll
      for (int r=0; r<4; r++){
        int row = m0 + wm + mt*16 + lg*4 + r;
        op[(size_t)row*C_ + col] = acc[mt][nt][r];
      }
    }
}

// ---------------------------------------------------------------------------
// K2: per-chunk KV summary: kv[b][ci][c][dd] = sum_j d^{L-1-j} k_j[c] v_j[dd]
// ---------------------------------------------------------------------------
__global__ __launch_bounds__(256) void kvsum_kernel(
    const float* __restrict__ k, const float* __restrict__ v,
    const float* __restrict__ dptr, float* __restrict__ kv)
{
  int ci = blockIdx.x, b = blockIdx.y;
  float d = sigmoidf_(dptr[0]);
  __shared__ float ks[L_][132];
  __shared__ float vs[L_][132];
  int tid = threadIdx.x;
  const float* kp = k + ((size_t)b*T_ + ci*L_)*C_;
  const float* vp = v + ((size_t)b*T_ + ci*L_)*C_;
  #pragma unroll
  for (int i=0;i<4;i++){
    int idx = tid + i*256;
    int j = idx >> 5, c4 = idx & 31;
    float w = powf(d, (float)(L_-1-j));
    float4 k4 = *(const float4*)(kp + (size_t)j*C_ + c4*4);
    k4.x*=w; k4.y*=w; k4.z*=w; k4.w*=w;
    *(float4*)&ks[j][c4*4] = k4;
    *(float4*)&vs[j][c4*4] = *(const float4*)(vp + (size_t)j*C_ + c4*4);
  }
  __syncthreads();
  int tc = tid >> 4, td = tid & 15;
  float acc[8][8] = {};
  for (int j=0;j<L_;j++){
    float kr[8], vr[8];
    *(float4*)&kr[0] = *(float4*)&ks[j][tc*8];
    *(float4*)&kr[4] = *(float4*)&ks[j][tc*8+4];
    *(float4*)&vr[0] = *(float4*)&vs[j][td*8];
    *(float4*)&vr[4] = *(float4*)&vs[j][td*8+4];
    #pragma unroll
    for (int a=0;a<8;a++)
      #pragma unroll
      for (int bb=0;bb<8;bb++) acc[a][bb] += kr[a]*vr[bb];
  }
  float* op = kv + ((size_t)b*NC_ + ci)*C_*C_;
  for (int a=0;a<8;a++)
    for (int b4=0;b4<2;b4++)
      *(float4*)(op + (size_t)(tc*8+a)*C_ + td*8 + b4*4) =
        make_float4(acc[a][b4*4],acc[a][b4*4+1],acc[a][b4*4+2],acc[a][b4*4+3]);
}

// ---------------------------------------------------------------------------
// K3: in-place exclusive scan over chunks
// ---------------------------------------------------------------------------
__global__ __launch_bounds__(256) void scan_kernel(
    float* __restrict__ kv, const float* __restrict__ dptr)
{
  int idx = blockIdx.x*256 + threadIdx.x;
  int b = idx >> 14, e = idx & 16383;
  float d  = sigmoidf_(dptr[0]);
  float dL = powf(d, (float)L_);
  float* p = kv + (size_t)b*NC_*C_*C_ + e;
  float m = 0.f;
  for (int i=0;i<NC_;i++){
    float s = p[(size_t)i*C_*C_];
    p[(size_t)i*C_*C_] = m;
    m = dL*m + s;
  }
}

// ---------------------------------------------------------------------------
// K4 (round-5 version, reverted): per-chunk retrieved; ret written as fp16.
// M chunks staged via global_load_lds DMA (zero VGPR cost). Chunk k+1's DMA
// issued right after the barrier that frees its buffer, drains at the NEXT
// barrier, hidden under chunk k's FMA. Round-6's column-split regressed
// (bank conflicts x3.6, scores duplicated, VGPR cap untouched) -- reverted.
// ---------------------------------------------------------------------------
__global__ __launch_bounds__(256, 4) void intra_kernel(
    const float* __restrict__ q, const float* __restrict__ k,
    const float* __restrict__ v, const float* __restrict__ Minit,
    const float* __restrict__ dptr,
    f16_t* __restrict__ ret)
{
  int ci = blockIdx.x, b = blockIdx.y;
  int tid = threadIdx.x;
  float d = sigmoidf_(dptr[0]);
  __shared__ float qs[L_][132];
  __shared__ float kvs[L_][132];            // k for scores, then v
  __shared__ __align__(16) float Ms[2][L_][C_];  // 32 KB, linear (DMA dest)
  __shared__ float ps[L_][33];
  __shared__ float dpow[L_+1];
  if (tid <= L_) dpow[tid] = powf(d, (float)tid);

  const float* qp = q + ((size_t)b*T_ + ci*L_)*C_;
  const float* kp = k + ((size_t)b*T_ + ci*L_)*C_;
  const float* vp = v + ((size_t)b*T_ + ci*L_)*C_;
  const float* Mp = Minit + ((size_t)b*NC_ + ci)*C_*C_;

  // ---- DMA chunk 0 -> Ms[0] (16 KB = 1024 x 16B, 4 per thread)
  #pragma unroll
  for (int i=0;i<4;i++){
    int cidx = i*256 + tid;
    gload_lds16(Mp + (size_t)cidx*4, &Ms[0][0][cidx*4]);
  }
  // ---- stage q, k
  #pragma unroll
  for (int i=0;i<4;i++){
    int idx = tid + i*256;
    int j = idx >> 5, c4 = idx & 31;
    *(float4*)&qs[j][c4*4]  = *(const float4*)(qp + (size_t)j*C_ + c4*4);
    *(float4*)&kvs[j][c4*4] = *(const float4*)(kp + (size_t)j*C_ + c4*4);
  }
  __syncthreads();   // B0: chunk0 + qs + kvs(k) visible

  // ---- DMA chunk 1 -> Ms[1] (drains at B1, hidden under scores)
  #pragma unroll
  for (int i=0;i<4;i++){
    int cidx = i*256 + tid;
    gload_lds16(Mp + (size_t)L_*C_ + cidx*4, &Ms[1][0][cidx*4]);
  }

  // ---- scores ps
  {
    int tr = tid >> 4, tj = tid & 15;
    float s[2][2] = {};
    for (int c4=0;c4<32;c4++){
      float4 q4[2], k4[2];
      #pragma unroll
      for (int i=0;i<2;i++) q4[i] = *(float4*)&qs[tr*2+i][c4*4];
      #pragma unroll
      for (int i=0;i<2;i++) k4[i] = *(float4*)&kvs[tj*2+i][c4*4];
      #pragma unroll
      for (int a=0;a<2;a++)
        #pragma unroll
        for (int bb=0;bb<2;bb++)
          s[a][bb] += q4[a].x*k4[bb].x + q4[a].y*k4[bb].y + q4[a].z*k4[bb].z + q4[a].w*k4[bb].w;
    }
    #pragma unroll
    for (int a=0;a<2;a++)
      #pragma unroll
      for (int bb=0;bb<2;bb++){
        int r = tr*2+a, j = tj*2+bb;
        ps[r][j] = (j < r) ? s[a][bb]*dpow[r-1-j] : 0.f;
      }
  }
  __syncthreads();   // B1: ps + chunk1 visible; kvs(k) dead

  // ---- stage v into kvs (read only after B2; its loads overlap MCHUNK(0,0))
  #pragma unroll
  for (int i=0;i<4;i++){
    int idx = tid + i*256;
    int j = idx >> 5, c4 = idx & 31;
    *(float4*)&kvs[j][c4*4] = *(const float4*)(vp + (size_t)j*C_ + c4*4);
  }

  int tx = tid & 31, ty = tid >> 5;
  float acc[4][4] = {};

#define INTRA_MCHUNK(buf, cc) do { \
    for (int c=0;c<L_;c++){ \
      float4 m4 = *(float4*)&Ms[buf][c][tx*4]; \
      _Pragma("unroll") \
      for (int r=0;r<4;r++){ \
        float qv = qs[ty*4+r][(cc)*L_ + c]; \
        acc[r][0] += qv*m4.x; acc[r][1] += qv*m4.y; \
        acc[r][2] += qv*m4.z; acc[r][3] += qv*m4.w; \
      } \
    } \
  } while(0)

  INTRA_MCHUNK(0, 0);
  __syncthreads();   // B2: Ms[0] reads done; kvs(v) visible

  // ---- DMA chunk 2 -> Ms[0] (drains at B3, hidden under MCHUNK(1,1))
  #pragma unroll
  for (int i=0;i<4;i++){
    int cidx = i*256 + tid;
    gload_lds16(Mp + (size_t)2*L_*C_ + cidx*4, &Ms[0][0][cidx*4]);
  }
  INTRA_MCHUNK(1, 1);
  __syncthreads();   // B3: chunk2 visible; Ms[1] reads done

  // ---- DMA chunk 3 -> Ms[1] (drains at B4, hidden under MCHUNK(0,2))
  #pragma unroll
  for (int i=0;i<4;i++){
    int cidx = i*256 + tid;
    gload_lds16(Mp + (size_t)3*L_*C_ + cidx*4, &Ms[1][0][cidx*4]);
  }
  INTRA_MCHUNK(0, 2);
  __syncthreads();   // B4: chunk3 visible

  INTRA_MCHUNK(1, 3);
#undef INTRA_MCHUNK

  #pragma unroll
  for (int r=0;r<4;r++){
    float sc = dpow[ty*4+r];
    #pragma unroll
    for (int j=0;j<4;j++) acc[r][j] *= sc;
  }
  for (int j=0;j<L_;j++){
    float4 v4 = *(float4*)&kvs[j][tx*4];
    #pragma unroll
    for (int r=0;r<4;r++){
      float p = ps[ty*4+r][j];
      acc[r][0] += p*v4.x; acc[r][1] += p*v4.y; acc[r][2] += p*v4.z; acc[r][3] += p*v4.w;
    }
  }
  size_t rbase = ((size_t)b*T_ + ci*L_)*C_;
  for (int r=0;r<4;r++){
    union { f16_t h[4]; ushort4 u; } hh;
    #pragma unroll
    for (int j=0;j<4;j++) hh.h[j] = (f16_t)acc[r][j];
    *(ushort4*)(ret + rbase + (size_t)(ty*4+r)*C_ + tx*4) = hh.u;
  }
}

// ---------------------------------------------------------------------------
// K5 v3: out = (ret @ Wo^T) * out_scale -- A-RESIDENT MFMA.
// Old grid (256,8) read ret 8x (256 MB via L2/L3). New: grid 256, 512 thr
// (8 waves, 2Mx4N). Block stages its 64x128 A-tile (ret, f16, 17 KB LDS)
// ONCE -- single barrier in the whole kernel -- then loops 4 N-passes of 256
// cols streaming Wo B-fragments directly from L2 (Wo = 256 KB, L2-resident).
// ret read 1x (32 MB), Wo ~64 MB L2, out 64 MB HBM write. 1 block/CU.
// ---------------------------------------------------------------------------
#define PADA 136   // A LDS row stride in f16 (272 B; rows advance 4 banks)

__global__ __launch_bounds__(512, 1) void out_mfma_kernel(
    const f16_t* __restrict__ A, const f16_t* __restrict__ Bw,
    const float* __restrict__ scl, float* __restrict__ out)
{
  int m0 = blockIdx.x * BM;     // 256 blocks x 64 rows
  float osc = scl[0];

  __shared__ __align__(16) f16_t As[BM][PADA];   // 17 KB

  int tid  = threadIdx.x;       // 0..511
  int lane = tid & 63;
  int w    = tid >> 6;          // 0..7
  int wm   = (w >> 2) * 32;     // 0,32
  int wn   = (w & 3) * 64;      // 0,64,128,192 within a 256-col pass
  int lr   = lane & 15;
  int lg   = lane >> 4;

  // stage A: 64 rows x 128 f16 = 1024 x 16B chunks, 2/thread
  #pragma unroll
  for (int i=0;i<2;i++){
    int ci = i*512 + tid;
    int row = ci >> 4, ch = ci & 15;
    *(uint4*)&As[row][ch*8] = *(const uint4*)(A + (size_t)(m0+row)*C_ + ch*8);
  }
  __syncthreads();   // the only barrier

  for (int p=0; p<4; p++){            // N-pass: cols p*256 .. p*256+255
    int n0 = p*256 + wn;
    f32x4 acc[2][4] = {};
    #pragma unroll
    for (int kh=0; kh<4; kh++){
      f16x8 a[2];
      #pragma unroll
      for (int mt=0; mt<2; mt++)
        a[mt] = *(f16x8*)&As[wm + mt*16 + lr][kh*32 + lg*8];
      #pragma unroll
      for (int nt=0; nt<4; nt++){
        f16x8 bfr = *(const f16x8*)(Bw + (size_t)(n0 + nt*16 + lr)*C_ + kh*32 + lg*8);
        #pragma unroll
        for (int mt=0; mt<2; mt++)
          acc[mt][nt] = __builtin_amdgcn_mfma_f32_16x16x32_f16(a[mt], bfr, acc[mt][nt], 0,0,0);
      }
    }
    #pragma unroll
    for (int mt=0; mt<2; mt++)
      #pragma unroll
      for (int nt=0; nt<4; nt++)
        #pragma unroll
        for (int r=0; r<4; r++){
          int row = m0 + wm + mt*16 + lg*4 + r;
          int col = n0 + nt*16 + lr;
          out[(size_t)row*V_ + col] = acc[mt][nt][r] * osc;
        }
  }
}

// ---------------------------------------------------------------------------
extern "C" void kernel_launch(void* const* d_in, const int* in_sizes, int n_in,
                              void* d_out, int out_size, void* d_ws, size_t ws_size,
                              hipStream_t stream)
{
  const float* x     = (const float*)d_in[0];
  const float* basis = (const float*)d_in[1];
  const float* qc    = (const float*)d_in[2];
  const float* kc    = (const float*)d_in[3];
  const float* vc    = (const float*)d_in[4];
  const float* oc    = (const float*)d_in[5];
  const float* dptr  = (const float*)d_in[6];
  const float* sptr  = (const float*)d_in[7];
  float* out = (float*)d_out;
  float* ws  = (float*)d_ws;

  const size_t M = (size_t)B_*T_;
  // Workspace layout (offsets in FLOAT units):
  //   Wo   f16 V*C      @ 0        (65536 f)
  //   Wt   f16 3*C*V    @ 65536    (196608 f)
  //   qkv  f32 3*M*C    @ 262144
  //   ret  f16 M*C      @ 6553600
  //   kv   f32 B*NC*C*C @ 7602176
  f16_t* Wo  = (f16_t*)ws;
  f16_t* Wt  = (f16_t*)(ws + 65536);
  float* qkv = ws + 262144;
  f16_t* ret = (f16_t*)(ws + 6553600);
  float* kv  = ws + 7602176;

  float* q = qkv;
  float* k = qkv + M*C_;
  float* v = qkv + 2*M*C_;

  hipLaunchKernelGGL(weights_kernel, dim3(512), dim3(256), 0, stream,
                     basis, qc, kc, vc, oc, Wo, Wt);
  hipLaunchKernelGGL(proj_fused_kernel, dim3(256), dim3(512), 0, stream,
                     x, Wt, qkv);
  hipLaunchKernelGGL(kvsum_kernel, dim3(NC_, B_), dim3(256), 0, stream, k, v, dptr, kv);
  hipLaunchKernelGGL(scan_kernel, dim3(512), dim3(256), 0, stream, kv, dptr);
  hipLaunchKernelGGL(intra_kernel, dim3(NC_, B_), dim3(256), 0, stream,
                     q, k, v, kv, dptr, ret);
  hipLaunchKernelGGL(out_mfma_kernel, dim3(256), dim3(512), 0, stream,
                     ret, Wo, sptr, out);
}